// Round 3
// baseline (569.504 us; speedup 1.0000x reference)
//
#include <hip/hip_runtime.h>
#include <stdint.h>

typedef __attribute__((ext_vector_type(8))) short short8;
typedef __attribute__((ext_vector_type(4))) float f32x4;
typedef __attribute__((ext_vector_type(2))) unsigned int u32x2;
typedef __attribute__((ext_vector_type(4))) unsigned int u32x4;

#define KDIM 8192
#define NDIM 8192
#define MDIM 64
#define NGRP 128
#define KT 64                  // output rows per block (16 per wave)
#define SPLIT 8                // split-K partials per output
#define NCHUNK (NDIM / SPLIT)  // 1024 input features per block
#define NSTEPS (NCHUNK / 64)   // 16 quant groups per block
#define XFRAG (MDIM * NDIM)    // shorts per x-fragment buffer (1 MB)
#define MK (MDIM * KDIM)       // floats per output / partial slab (2 MB)

__device__ __forceinline__ short f2bf(float v) {
  unsigned u = __builtin_bit_cast(unsigned, v);
  u += 0x7FFFu + ((u >> 16) & 1u);  // round-to-nearest-even
  return (short)(u >> 16);
}
__device__ __forceinline__ float bf2f(short h) {
  unsigned u = ((unsigned)(unsigned short)h) << 16;
  return __builtin_bit_cast(float, u);
}

// out[m,k] = bias[k]  (atomic-path init)
__global__ void init_out_kernel(const float* __restrict__ bias, float* __restrict__ out) {
  int i = blockIdx.x * blockDim.x + threadIdx.x;  // 131072 float4 stores
  f32x4 b = ((const f32x4*)bias)[i & (KDIM / 4 - 1)];
  ((f32x4*)out)[i] = b;
}

// out[m,k] = bias[k] + sum_s pw[s][m][k]  (ws-path reduction, no atomics)
__global__ void reduce_kernel(const float* __restrict__ pw, const float* __restrict__ bias,
                              float* __restrict__ out) {
  int i = blockIdx.x * blockDim.x + threadIdx.x;  // 131072 float4
  f32x4 acc = ((const f32x4*)bias)[i & (KDIM / 4 - 1)];
#pragma unroll
  for (int s = 0; s < SPLIT; ++s) acc += ((const f32x4*)pw)[s * (MK / 4) + i];
  ((f32x4*)out)[i] = acc;
}

// x' = x*mu1 split into bf16 high (xfH) + bf16 residual (xfL), stored in MFMA
// A-frag order: frag(nblk,mblk): lane l holds x'[mblk*16+(l&15)][nblk*32+(l>>4)*8+i]
__global__ void prep_xf_kernel(const float* __restrict__ x, const float* __restrict__ mu1,
                               short* __restrict__ xfH, short* __restrict__ xfL) {
  int tid = blockIdx.x * blockDim.x + threadIdx.x;  // 65536 threads
  int l = tid & 63;
  int mblk = (tid >> 6) & 3;
  int nblk = tid >> 8;
  int m = mblk * 16 + (l & 15);
  int nb = nblk * 32 + (l >> 4) * 8;  // multiple of 8 -> 32B aligned
  const float* xr = x + (size_t)m * NDIM + nb;
  f32x4 x0 = *(const f32x4*)xr;
  f32x4 x1 = *(const f32x4*)(xr + 4);
  f32x4 u0 = *(const f32x4*)(mu1 + nb);
  f32x4 u1 = *(const f32x4*)(mu1 + nb + 4);
  short8 hv, lv;
#pragma unroll
  for (int i = 0; i < 8; ++i) {
    float xv = (i < 4) ? x0[i & 3] * u0[i & 3] : x1[i & 3] * u1[i & 3];
    short h = f2bf(xv);
    hv[i] = h;
    lv[i] = f2bf(xv - bf2f(h));  // exact subtraction (h within 2^-8 of xv)
  }
  *(short8*)(xfH + (size_t)tid * 8) = hv;
  *(short8*)(xfL + (size_t)tid * 8) = lv;
}

// Barrier-free GEMM: each wave owns 16 output cols; B-fragments dequantized
// per-lane directly from global (lane reads exactly its fragment's 8 weights).
// ATOMIC=true: accumulate into out (bias pre-initialized).
// ATOMIC=false: plain stores of this block's partial into pw[s].
template <bool I32, bool ATOMIC>
__device__ __forceinline__ void gemm_body(const void* __restrict__ wq,
                                          const float* __restrict__ scales,
                                          const float* __restrict__ zeros,
                                          const float* __restrict__ mask,
                                          const float* __restrict__ mu2,
                                          const short* __restrict__ xfH,
                                          const short* __restrict__ xfL,
                                          float* __restrict__ outp) {
  const int bx = blockIdx.x;
  const int kt = bx >> 3;  // K-tile (0..127)
  const int s = bx & 7;    // N-split (0..7)
  const int k0 = kt * KT;
  const int n0 = s * NCHUNK;
  const int tid = threadIdx.x;
  const int w = tid >> 6;  // wave: owns cols [k0+16w, k0+16w+16)
  const int l = tid & 63;
  const int row = l & 15;  // B-frag: output col within wave tile
  const int g4 = l >> 4;   // B-frag: k-group (features 8*g4..8*g4+7)
  const int kc = k0 + w * 16 + row;
  const float mu2k = mu2[kc];

  const float* mrow = mask + (size_t)kc * NDIM + n0 + g4 * 8;
  const uint8_t* q8row = (const uint8_t*)wq + (size_t)kc * NDIM + n0 + g4 * 8;
  const int* q32row = (const int*)wq + (size_t)kc * NDIM + n0 + g4 * 8;
  const float* srow = scales + (size_t)kc * NGRP + (n0 >> 6);
  const float* zrow = zeros + (size_t)kc * NGRP + (n0 >> 6);
  const short8* a8H = (const short8*)xfH;
  const short8* a8L = (const short8*)xfL;

  f32x4 acc[4] = {};  // 4 token-blocks x f32x4

  for (int st = 0; st < NSTEPS; ++st) {
    const int off = st * 64;
    const float se = srow[st] * mu2k;
    const float nz = -zrow[st] * se;
    short8 bh[2], bl[2];
#pragma unroll
    for (int sub = 0; sub < 2; ++sub) {
      // lane's 8 weights: 32B contiguous mask + 8B contiguous W_q
      f32x4 m0 = *(const f32x4*)(mrow + off + sub * 32);
      f32x4 m1 = *(const f32x4*)(mrow + off + sub * 32 + 4);
      u32x2 q8;
      u32x4 qa, qb;
      if constexpr (I32) {
        qa = *(const u32x4*)(q32row + off + sub * 32);
        qb = *(const u32x4*)(q32row + off + sub * 32 + 4);
      } else {
        q8 = *(const u32x2*)(q8row + off + sub * 32);
      }
#pragma unroll
      for (int i = 0; i < 8; ++i) {
        float qf;
        if constexpr (I32)
          qf = (float)(int)((i < 4) ? qa[i & 3] : qb[i & 3]);
        else
          qf = (float)((q8[i >> 2] >> (8 * (i & 3))) & 0xFFu);  // v_cvt_f32_ubyte
        float mv = (i < 4) ? m0[i & 3] : m1[i & 3];
        float wv = fmaf(qf, se, nz) * mv;  // ((q-z)*s*mu2)*mask, fp32
        short h = f2bf(wv);
        bh[sub][i] = h;
        bl[sub][i] = f2bf(wv - bf2f(h));  // bf16 residual
      }
    }
    // split-bf16 3-MFMA: xh*wh + xh*wl + xl*wh (drops only xl*wl ~ 2^-17 rel)
    const int nblk0 = (n0 + off) >> 5;
#pragma unroll
    for (int sub = 0; sub < 2; ++sub) {
      const short8* apH = a8H + (size_t)(nblk0 + sub) * 256 + l;
      const short8* apL = a8L + (size_t)(nblk0 + sub) * 256 + l;
#pragma unroll
      for (int mb = 0; mb < 4; ++mb) {
        short8 ah = apH[mb * 64];
        short8 al = apL[mb * 64];
        acc[mb] = __builtin_amdgcn_mfma_f32_16x16x32_bf16(ah, bh[sub], acc[mb], 0, 0, 0);
        acc[mb] = __builtin_amdgcn_mfma_f32_16x16x32_bf16(ah, bl[sub], acc[mb], 0, 0, 0);
        acc[mb] = __builtin_amdgcn_mfma_f32_16x16x32_bf16(al, bh[sub], acc[mb], 0, 0, 0);
      }
    }
  }

  // C/D layout (m89-verified): col=lane&15 -> output k, row=(lane>>4)*4+j -> token m
#pragma unroll
  for (int mb = 0; mb < 4; ++mb) {
#pragma unroll
    for (int j = 0; j < 4; ++j) {
      int m = mb * 16 + g4 * 4 + j;
      if constexpr (ATOMIC)
        atomicAdd(outp + (size_t)m * KDIM + kc, acc[mb][j]);
      else  // per-instr: 4 rows x 64B contiguous -> full-line wave stores
        outp[(size_t)s * MK + (size_t)m * KDIM + kc] = acc[mb][j];
    }
  }
}

template <bool ATOMIC>
__global__ void __launch_bounds__(256, 4) gemm_kernel(
    const void* __restrict__ wq, const float* __restrict__ scales,
    const float* __restrict__ zeros, const float* __restrict__ mask,
    const float* __restrict__ mu2, const short* __restrict__ xfH,
    const short* __restrict__ xfL, float* __restrict__ outp) {
  // Self-detect W_q element width: packed int8 nibbles make words > 15 a.s.
  const unsigned* wqu = (const unsigned*)wq;
  bool i32m = true;
#pragma unroll
  for (int i = 0; i < 16; ++i) i32m &= (wqu[i] <= 15u);
  if (i32m)
    gemm_body<true, ATOMIC>(wq, scales, zeros, mask, mu2, xfH, xfL, outp);
  else
    gemm_body<false, ATOMIC>(wq, scales, zeros, mask, mu2, xfH, xfL, outp);
}

extern "C" void kernel_launch(void* const* d_in, const int* in_sizes, int n_in,
                              void* d_out, int out_size, void* d_ws, size_t ws_size,
                              hipStream_t stream) {
  const float* x = (const float*)d_in[0];
  const void* wq = d_in[1];
  const float* scales = (const float*)d_in[2];
  const float* zeros = (const float*)d_in[3];
  const float* mask = (const float*)d_in[4];
  const float* mu1 = (const float*)d_in[5];
  const float* mu2 = (const float*)d_in[6];
  const float* bias = (const float*)d_in[7];
  float* out = (float*)d_out;
  short* xfH = (short*)d_ws;  // 1 MB
  short* xfL = xfH + XFRAG;   // 1 MB
  float* pw = (float*)(xfL + XFRAG);  // 16 MB split-K partials (ws path)

  const size_t need_ws = 2u * XFRAG * sizeof(short) + (size_t)SPLIT * MK * sizeof(float);
  const bool use_ws = ws_size >= need_ws;  // constant per process -> graph-safe

  prep_xf_kernel<<<dim3(256), dim3(256), 0, stream>>>(x, mu1, xfH, xfL);
  if (use_ws) {
    // no atomics: partials to ws, then deterministic reduction (+bias)
    gemm_kernel<false><<<dim3((KDIM / KT) * SPLIT), dim3(256), 0, stream>>>(
        wq, scales, zeros, mask, mu2, xfH, xfL, pw);
    reduce_kernel<<<dim3(512), dim3(256), 0, stream>>>(pw, bias, out);
  } else {
    init_out_kernel<<<dim3(512), dim3(256), 0, stream>>>(bias, out);
    gemm_kernel<true><<<dim3((KDIM / KT) * SPLIT), dim3(256), 0, stream>>>(
        wq, scales, zeros, mask, mu2, xfH, xfL, out);
  }
}